// Round 4
// baseline (296.703 us; speedup 1.0000x reference)
//
#include <hip/hip_runtime.h>
#include <hip/hip_bf16.h>

// Problem constants: B=4, N=4096, DIM=1024; qkva = [B*N, 3*DIM]
#define SEQ_N 4096
#define BATCH 4
#define DIM 1024
#define M_ROWS (BATCH * SEQ_N)      // 16384
#define NCOLS (3 * DIM)             // 3072
#define KDIM DIM                    // 1024
#define CHUNK_L 16
#define NCHUNK (SEQ_N / CHUNK_L)    // 256
#define NCHANNEL (BATCH * DIM)      // 4096
#define GT 32                       // K / 32 k-tiles for the 256x256 GEMM

using short8 = __attribute__((ext_vector_type(8))) short;
using f32x4  = __attribute__((ext_vector_type(4))) float;

static __device__ __forceinline__ unsigned short f2bf(float f) {
    union { float f; unsigned u; } v; v.f = f;
    unsigned r = v.u + 0x7fffu + ((v.u >> 16) & 1u);   // round-to-nearest-even
    return (unsigned short)(r >> 16);
}
static __device__ __forceinline__ float bf2f(unsigned short s) {
    union { unsigned u; float f; } v; v.u = ((unsigned)s) << 16;
    return v.f;
}
static __device__ __forceinline__ float sigm(float x) {
    return 1.f / (1.f + __expf(-x));
}

// ---------------- fused: w fp32->bf16 (blocks 0..3071) + RMSNorm (blocks 3072..) ----
#define WCONV_BLOCKS 3072           // NCOLS*KDIM/4/256
__global__ __launch_bounds__(256) void pre_kernel(const float* __restrict__ w,
                                                  unsigned short* __restrict__ wb,
                                                  const float* __restrict__ x,
                                                  const float* __restrict__ gamma,
                                                  unsigned short* __restrict__ h) {
    const int bid = blockIdx.x;
    const int tid = threadIdx.x;
    if (bid < WCONV_BLOCKS) {
        const int i = bid * 256 + tid;
        float4 v = reinterpret_cast<const float4*>(w)[i];
        ushort4 o;
        o.x = f2bf(v.x); o.y = f2bf(v.y); o.z = f2bf(v.z); o.w = f2bf(v.w);
        reinterpret_cast<ushort4*>(wb)[i] = o;
        return;
    }
    const int row = bid - WCONV_BLOCKS;
    const float4 v = reinterpret_cast<const float4*>(x + (size_t)row * DIM)[tid];
    float ss = v.x * v.x + v.y * v.y + v.z * v.z + v.w * v.w;
#pragma unroll
    for (int off = 32; off >= 1; off >>= 1) ss += __shfl_xor(ss, off, 64);
    __shared__ float red[4];
    if ((tid & 63) == 0) red[tid >> 6] = ss;
    __syncthreads();
    const float tot = red[0] + red[1] + red[2] + red[3];
    const float scale = 32.0f / fmaxf(sqrtf(tot), 1e-12f);   // sqrt(1024)=32
    const float4 g = reinterpret_cast<const float4*>(gamma)[tid];
    ushort4 o;
    o.x = f2bf(v.x * scale * g.x);
    o.y = f2bf(v.y * scale * g.y);
    o.z = f2bf(v.z * scale * g.z);
    o.w = f2bf(v.w * scale * g.w);
    reinterpret_cast<ushort4*>(h + (size_t)row * DIM)[tid] = o;
}

// ---------------- GEMM: C[m,e] = sum_k A[m,k] * B[e,k], bf16 in, bf16 out ----
// 256x256 tile, BK=32, 4-deep LDS rotation, 8 waves (2Mx4N).
// BARRIER-MINIMAL schedule: exactly ONE {vmcnt(4); s_barrier} per K-tile
// (publishes tile t+1's staged loads). Within a tile, ds_read / gload_lds /
// 32 MFMA are left unfenced so the compiler emits fine-grained lgkmcnt
// interleave and the 2 waves/SIMD desync (LDS drain of one wave hides under
// the other's MFMA). Hazard audit: staging at tile t writes buffer (t+2)&3,
// last read at tile t-2 -> separated by two tile-end barriers; reads at tile
// t touch buffer t&3 whose loads were vmcnt-published at end of t-1.
// T1 bijective XCD swizzle; T2 16B-granule XOR swizzle (source+read, rule #21).
__global__ __launch_bounds__(512, 2) void gemm256_kernel(const unsigned short* __restrict__ A,
                                                         const unsigned short* __restrict__ B,
                                                         unsigned short* __restrict__ C) {
    __shared__ __align__(16) unsigned short sA[4][256][32];   // 64 KiB
    __shared__ __align__(16) unsigned short sB[4][256][32];   // 64 KiB

    const int tid  = threadIdx.x;
    const int lane = tid & 63;
    const int wave = tid >> 6;

    // T1: bijective XCD swizzle (nwg = 768 = 8 * 96)
    const int orig = blockIdx.x;
    const int swz  = (orig & 7) * 96 + (orig >> 3);
    const int ntile = swz >> 6;           // 0..11
    const int mtile = swz & 63;           // 0..63
    const int row0 = mtile * 256;
    const int col0 = ntile * 256;

    const int wm = (wave >> 2) * 128;     // 0 or 128
    const int wn = (wave & 3) * 64;       // 0,64,128,192
    const int fr = lane & 15;             // frag row/col within 16x16
    const int kq = lane >> 4;             // k-quad (which 8 of K=32)
    const int kqx = kq ^ ((fr >> 1) & 3); // T2 swizzled granule (per-lane const)

    // staging: 512 thr x 16B = 8KB per unit; unit covers 128 rows; T2 source perm
    const int srow = tid >> 2;            // 0..127
    const int scol = ((tid & 3) ^ ((srow >> 1) & 3)) * 8;   // swizzled global granule
    const unsigned short* aSrc = A + (size_t)(row0 + srow) * KDIM + scol;
    const unsigned short* bSrc = B + (size_t)(col0 + srow) * KDIM + scol;
    unsigned short* sAf = &sA[0][0][0];
    unsigned short* sBf = &sB[0][0][0];
    const int sdst = tid * 8;             // linear LDS dest (element offset)

#define STAGE_A(bs, kt, u)                                                              \
    __builtin_amdgcn_global_load_lds(                                                   \
        (const __attribute__((address_space(1))) void*)(aSrc + (size_t)(u) * 128 * KDIM + (kt) * 32), \
        (__attribute__((address_space(3))) void*)(sAf + (bs) * 8192 + (u) * 4096 + sdst), 16, 0, 0);
#define STAGE_B(bs, kt, u)                                                              \
    __builtin_amdgcn_global_load_lds(                                                   \
        (const __attribute__((address_space(1))) void*)(bSrc + (size_t)(u) * 128 * KDIM + (kt) * 32), \
        (__attribute__((address_space(3))) void*)(sBf + (bs) * 8192 + (u) * 4096 + sdst), 16, 0, 0);

    f32x4 acc[8][4] = {};

    // prologue: stage tiles 0 and 1 (8 loads), wait for tile 0 (4 left in flight)
    STAGE_A(0, 0, 0); STAGE_A(0, 0, 1); STAGE_B(0, 0, 0); STAGE_B(0, 0, 1);
    STAGE_A(1, 1, 0); STAGE_A(1, 1, 1); STAGE_B(1, 1, 0); STAGE_B(1, 1, 1);
    asm volatile("s_waitcnt vmcnt(4)" ::: "memory");
    __builtin_amdgcn_sched_barrier(0);
    __builtin_amdgcn_s_barrier();

    // invariant entering tile t: tiles <= t landed (all waves); only t+1's loads outstanding
    for (int t = 0; t < GT; ++t) {
        const int b  = t & 3;
        const int bs = (t + 2) & 3;
        const bool st = (t + 2 < GT);
        const unsigned short* sAb = sAf + b * 8192;
        const unsigned short* sBb = sBf + b * 8192;

        short8 bfr[4], afr[4], afr2[4];
#pragma unroll
        for (int j = 0; j < 4; ++j)
            bfr[j] = *reinterpret_cast<const short8*>(sBb + (wn + j * 16 + fr) * 32 + kqx * 8);
#pragma unroll
        for (int i = 0; i < 4; ++i)
            afr[i] = *reinterpret_cast<const short8*>(sAb + (wm + i * 16 + fr) * 32 + kqx * 8);
#pragma unroll
        for (int i = 0; i < 4; ++i)
            afr2[i] = *reinterpret_cast<const short8*>(sAb + (wm + 64 + i * 16 + fr) * 32 + kqx * 8);

        if (st) { STAGE_A(bs, t + 2, 0); STAGE_A(bs, t + 2, 1);
                  STAGE_B(bs, t + 2, 0); STAGE_B(bs, t + 2, 1); }

        __builtin_amdgcn_s_setprio(1);
#pragma unroll
        for (int i = 0; i < 4; ++i)
#pragma unroll
            for (int j = 0; j < 4; ++j)
                acc[i][j] = __builtin_amdgcn_mfma_f32_16x16x32_bf16(afr[i], bfr[j], acc[i][j], 0, 0, 0);
#pragma unroll
        for (int i = 0; i < 4; ++i)
#pragma unroll
            for (int j = 0; j < 4; ++j)
                acc[4 + i][j] = __builtin_amdgcn_mfma_f32_16x16x32_bf16(afr2[i], bfr[j], acc[4 + i][j], 0, 0, 0);
        __builtin_amdgcn_s_setprio(0);

        // single per-tile publish: tile t+1's loads must land before next tile's reads
        if (t < GT - 2) {
            asm volatile("s_waitcnt vmcnt(4)" ::: "memory");
        } else if (t == GT - 2) {
            asm volatile("s_waitcnt vmcnt(0)" ::: "memory");
        }
        __builtin_amdgcn_sched_barrier(0);
        __builtin_amdgcn_s_barrier();
    }
#undef STAGE_A
#undef STAGE_B

    // epilogue: C/D layout col=lane&15, row=(lane>>4)*4+reg
#pragma unroll
    for (int i = 0; i < 8; ++i) {
#pragma unroll
        for (int j = 0; j < 4; ++j) {
#pragma unroll
            for (int r = 0; r < 4; ++r) {
                int row = row0 + wm + i * 16 + kq * 4 + r;
                int col = col0 + wn + j * 16 + fr;
                C[(size_t)row * NCOLS + col] = f2bf(acc[i][j][r]);
            }
        }
    }
}

// ---------------- Scan phase 1: per-chunk aggregates (A = prod a, Y = local state)
// Writes aggregates TRANSPOSED [channel][chunk] for coalesced scan-phase loads.
__global__ __launch_bounds__(256) void chunk_agg_kernel(const unsigned short* __restrict__ qkva,
                                                        float* __restrict__ AaggT,
                                                        float* __restrict__ YaggT) {
    const int c = blockIdx.x, b = blockIdx.y;
    const int d4 = threadIdx.x * 4;                  // channel group base (0..1020)
    const unsigned short* base = qkva + ((size_t)b * SEQ_N + c * CHUNK_L) * NCOLS;
    float s[4] = {0.f, 0.f, 0.f, 0.f};
    float A[4] = {1.f, 1.f, 1.f, 1.f};
#pragma unroll 4
    for (int n = 0; n < CHUNK_L; ++n) {
        const ushort4 kvu = *reinterpret_cast<const ushort4*>(base + (size_t)n * NCOLS + DIM + d4);
        const ushort4 au  = *reinterpret_cast<const ushort4*>(base + (size_t)n * NCOLS + 2 * DIM + d4);
        const float kv[4] = {bf2f(kvu.x), bf2f(kvu.y), bf2f(kvu.z), bf2f(kvu.w)};
        const float av[4] = {bf2f(au.x),  bf2f(au.y),  bf2f(au.z),  bf2f(au.w)};
#pragma unroll
        for (int j = 0; j < 4; ++j) {
            const float a = sigm(av[j]);
            s[j] = fmaf(a, s[j], kv[j]);
            A[j] *= a;
        }
    }
#pragma unroll
    for (int j = 0; j < 4; ++j) {
        const size_t ch = (size_t)b * DIM + d4 + j;
        AaggT[ch * NCHUNK + c] = A[j];
        YaggT[ch * NCHUNK + c] = s[j];
    }
}

// ---------------- Scan phase 2: wave-parallel scan over chunk aggregates
// One wave per channel; lane t serially composes chunks 4t..4t+3, then a
// 6-step shfl_up inclusive scan of the (a,y) composition operator.
// Sin stays in [chunk][channel] layout so apply_kernel is unchanged.
__global__ __launch_bounds__(256) void agg_scan_kernel(const float* __restrict__ AaggT,
                                                       const float* __restrict__ YaggT,
                                                       float* __restrict__ Sin) {
    const int lane = threadIdx.x & 63;
    const int wv   = threadIdx.x >> 6;
    const int ch   = blockIdx.x * 4 + wv;            // 0..4095
    const float4 Av = *reinterpret_cast<const float4*>(&AaggT[(size_t)ch * NCHUNK + 4 * lane]);
    const float4 Yv = *reinterpret_cast<const float4*>(&YaggT[(size_t)ch * NCHUNK + 4 * lane]);
    const float Ac[4] = {Av.x, Av.y, Av.z, Av.w};
    const float Yc[4] = {Yv.x, Yv.y, Yv.z, Yv.w};
    // serial compose of this lane's 4 chunks: seg = chunk(4t)..chunk(4t+3)
    float a = 1.f, y = 0.f;
#pragma unroll
    for (int i = 0; i < 4; ++i) {
        y = fmaf(Ac[i], y, Yc[i]);
        a = a * Ac[i];
    }
    // inclusive wave scan (earlier segment from lane-off composed before current)
#pragma unroll
    for (int off = 1; off < 64; off <<= 1) {
        const float ap = __shfl_up(a, off, 64);
        const float yp = __shfl_up(y, off, 64);
        if (lane >= off) {
            y = fmaf(a, yp, y);
            a = a * ap;
        }
    }
    // exclusive prefix for this lane
    float ey = __shfl_up(y, 1, 64);
    if (lane == 0) ey = 0.f;
    // emit entry states for chunks 4t..4t+3
    float s = ey;
#pragma unroll
    for (int i = 0; i < 4; ++i) {
        Sin[(size_t)(4 * lane + i) * NCHANNEL + ch] = s;
        s = fmaf(Ac[i], s, Yc[i]);
    }
}

// ---------------- Scan phase 3: rescan chunk with correct entry state, out = q*y
__global__ __launch_bounds__(256) void apply_kernel(const unsigned short* __restrict__ qkva,
                                                    const float* __restrict__ Sin,
                                                    float* __restrict__ out) {
    const int c = blockIdx.x, b = blockIdx.y;
    const int d4 = threadIdx.x * 4;
    const unsigned short* base = qkva + ((size_t)b * SEQ_N + c * CHUNK_L) * NCOLS;
    float* obase = out + ((size_t)b * SEQ_N + c * CHUNK_L) * DIM;
    const float4 s0 = *reinterpret_cast<const float4*>(&Sin[(size_t)c * NCHANNEL + b * DIM + d4]);
    float s[4] = {s0.x, s0.y, s0.z, s0.w};
#pragma unroll 4
    for (int n = 0; n < CHUNK_L; ++n) {
        const ushort4 qu  = *reinterpret_cast<const ushort4*>(base + (size_t)n * NCOLS + d4);
        const ushort4 kvu = *reinterpret_cast<const ushort4*>(base + (size_t)n * NCOLS + DIM + d4);
        const ushort4 au  = *reinterpret_cast<const ushort4*>(base + (size_t)n * NCOLS + 2 * DIM + d4);
        const float kv[4] = {bf2f(kvu.x), bf2f(kvu.y), bf2f(kvu.z), bf2f(kvu.w)};
        const float av[4] = {bf2f(au.x),  bf2f(au.y),  bf2f(au.z),  bf2f(au.w)};
        const float q[4]  = {bf2f(qu.x),  bf2f(qu.y),  bf2f(qu.z),  bf2f(qu.w)};
        float4 o;
#pragma unroll
        for (int j = 0; j < 4; ++j) {
            const float a = sigm(av[j]);
            s[j] = fmaf(a, s[j], kv[j]);
        }
        o.x = q[0] * s[0]; o.y = q[1] * s[1]; o.z = q[2] * s[2]; o.w = q[3] * s[3];
        *reinterpret_cast<float4*>(&obase[(size_t)n * DIM + d4]) = o;
    }
}

extern "C" void kernel_launch(void* const* d_in, const int* in_sizes, int n_in,
                              void* d_out, int out_size, void* d_ws, size_t ws_size,
                              hipStream_t stream) {
    const float* x     = (const float*)d_in[0];   // [4,4096,1024]
    const float* w     = (const float*)d_in[1];   // [3072,1024]
    const float* gamma = (const float*)d_in[2];   // [1024]
    float* out = (float*)d_out;                   // [4,4096,1024]

    char* ws = (char*)d_ws;
    // workspace layout (bytes):
    unsigned short* wb   = (unsigned short*)(ws);                         // 3072*1024*2   = 6,291,456
    unsigned short* h    = (unsigned short*)(ws + 6291456);               // 16384*1024*2  = 33,554,432
    unsigned short* qkva = (unsigned short*)(ws + 39845888);              // 16384*3072*2  = 100,663,296
    // scan temporaries alias the h region (h is dead after the GEMM):
    // NCHANNEL*NCHUNK*4 = 4096*256*4 = 4,194,304 each
    float* AaggT = (float*)(ws + 6291456);
    float* YaggT = (float*)(ws + 6291456 + 4194304);
    float* Sin   = (float*)(ws + 6291456 + 8388608);

    pre_kernel<<<WCONV_BLOCKS + M_ROWS, 256, 0, stream>>>(w, wb, x, gamma, h);
    gemm256_kernel<<<(M_ROWS / 256) * (NCOLS / 256), 512, 0, stream>>>(h, wb, qkva);
    chunk_agg_kernel<<<dim3(NCHUNK, BATCH), 256, 0, stream>>>(qkva, AaggT, YaggT);
    agg_scan_kernel<<<NCHANNEL / 4, 256, 0, stream>>>(AaggT, YaggT, Sin);
    apply_kernel<<<dim3(NCHUNK, BATCH), 256, 0, stream>>>(qkva, Sin, out);
}

// Round 5
// 273.815 us; speedup vs baseline: 1.0836x; 1.0836x over previous
//
#include <hip/hip_runtime.h>
#include <hip/hip_bf16.h>

// Problem constants: B=4, N=4096, DIM=1024; qkva = [B*N, 3*DIM]
#define SEQ_N 4096
#define BATCH 4
#define DIM 1024
#define M_ROWS (BATCH * SEQ_N)      // 16384
#define NCOLS (3 * DIM)             // 3072
#define KDIM DIM                    // 1024
#define CHUNK_L 16
#define NCHUNK (SEQ_N / CHUNK_L)    // 256
#define NCHANNEL (BATCH * DIM)      // 4096
#define GT 32                       // K / 32 k-tiles for the 256x256 GEMM

using short8 = __attribute__((ext_vector_type(8))) short;
using f32x4  = __attribute__((ext_vector_type(4))) float;

static __device__ __forceinline__ unsigned short f2bf(float f) {
    union { float f; unsigned u; } v; v.f = f;
    unsigned r = v.u + 0x7fffu + ((v.u >> 16) & 1u);   // round-to-nearest-even
    return (unsigned short)(r >> 16);
}
static __device__ __forceinline__ float bf2f(unsigned short s) {
    union { unsigned u; float f; } v; v.u = ((unsigned)s) << 16;
    return v.f;
}
static __device__ __forceinline__ float sigm(float x) {
    return 1.f / (1.f + __expf(-x));
}

// ---------------- fused: w fp32->bf16 (blocks 0..3071) + RMSNorm (blocks 3072..) ----
#define WCONV_BLOCKS 3072           // NCOLS*KDIM/4/256
__global__ __launch_bounds__(256) void pre_kernel(const float* __restrict__ w,
                                                  unsigned short* __restrict__ wb,
                                                  const float* __restrict__ x,
                                                  const float* __restrict__ gamma,
                                                  unsigned short* __restrict__ h) {
    const int bid = blockIdx.x;
    const int tid = threadIdx.x;
    if (bid < WCONV_BLOCKS) {
        const int i = bid * 256 + tid;
        float4 v = reinterpret_cast<const float4*>(w)[i];
        ushort4 o;
        o.x = f2bf(v.x); o.y = f2bf(v.y); o.z = f2bf(v.z); o.w = f2bf(v.w);
        reinterpret_cast<ushort4*>(wb)[i] = o;
        return;
    }
    const int row = bid - WCONV_BLOCKS;
    const float4 v = reinterpret_cast<const float4*>(x + (size_t)row * DIM)[tid];
    float ss = v.x * v.x + v.y * v.y + v.z * v.z + v.w * v.w;
#pragma unroll
    for (int off = 32; off >= 1; off >>= 1) ss += __shfl_xor(ss, off, 64);
    __shared__ float red[4];
    if ((tid & 63) == 0) red[tid >> 6] = ss;
    __syncthreads();
    const float tot = red[0] + red[1] + red[2] + red[3];
    const float scale = 32.0f / fmaxf(sqrtf(tot), 1e-12f);   // sqrt(1024)=32
    const float4 g = reinterpret_cast<const float4*>(gamma)[tid];
    ushort4 o;
    o.x = f2bf(v.x * scale * g.x);
    o.y = f2bf(v.y * scale * g.y);
    o.z = f2bf(v.z * scale * g.z);
    o.w = f2bf(v.w * scale * g.w);
    reinterpret_cast<ushort4*>(h + (size_t)row * DIM)[tid] = o;
}

// ---------------- GEMM: C[m,e] = sum_k A[m,k] * B[e,k], bf16 in, bf16 out ----
// 256x256 tile, BK=32, 4-deep LDS rotation, 8 waves (2Mx4N), barrier-minimal
// (one {vmcnt; s_barrier} per K-tile). T2 16B-granule XOR swizzle (source+read).
// XCD swizzle v2: mtile-MAJOR within each XCD (12 consecutive blocks share one
// 512KB A-panel -> L2-resident; B = 6MB total -> L3-resident). This attacks the
// measured 5x A-overfetch (FETCH 202MB vs 40MB inputs) that made the per-tile
// staging wait HBM-BW-bound (4.4 B/cy/CU < 16KB/2832cy needed).
__global__ __launch_bounds__(512, 2) void gemm256_kernel(const unsigned short* __restrict__ A,
                                                         const unsigned short* __restrict__ B,
                                                         unsigned short* __restrict__ C) {
    __shared__ __align__(16) unsigned short sA[4][256][32];   // 64 KiB
    __shared__ __align__(16) unsigned short sB[4][256][32];   // 64 KiB

    const int tid  = threadIdx.x;
    const int lane = tid & 63;
    const int wave = tid >> 6;

    // T1 v2: bijective, mtile-major per XCD. nwg = 768 = 8 XCD * 96.
    const int orig = blockIdx.x;
    const int xcd  = orig & 7;
    const int q    = orig >> 3;           // 0..95
    const int mtile = xcd * 8 + q / 12;   // 0..63
    const int ntile = q % 12;             // 0..11
    const int row0 = mtile * 256;
    const int col0 = ntile * 256;

    const int wm = (wave >> 2) * 128;     // 0 or 128
    const int wn = (wave & 3) * 64;       // 0,64,128,192
    const int fr = lane & 15;             // frag row/col within 16x16
    const int kq = lane >> 4;             // k-quad (which 8 of K=32)
    const int kqx = kq ^ ((fr >> 1) & 3); // T2 swizzled granule (per-lane const)

    // staging: 512 thr x 16B = 8KB per unit; unit covers 128 rows; T2 source perm
    const int srow = tid >> 2;            // 0..127
    const int scol = ((tid & 3) ^ ((srow >> 1) & 3)) * 8;   // swizzled global granule
    const unsigned short* aSrc = A + (size_t)(row0 + srow) * KDIM + scol;
    const unsigned short* bSrc = B + (size_t)(col0 + srow) * KDIM + scol;
    unsigned short* sAf = &sA[0][0][0];
    unsigned short* sBf = &sB[0][0][0];
    const int sdst = tid * 8;             // linear LDS dest (element offset)

#define STAGE_A(bs, kt, u)                                                              \
    __builtin_amdgcn_global_load_lds(                                                   \
        (const __attribute__((address_space(1))) void*)(aSrc + (size_t)(u) * 128 * KDIM + (kt) * 32), \
        (__attribute__((address_space(3))) void*)(sAf + (bs) * 8192 + (u) * 4096 + sdst), 16, 0, 0);
#define STAGE_B(bs, kt, u)                                                              \
    __builtin_amdgcn_global_load_lds(                                                   \
        (const __attribute__((address_space(1))) void*)(bSrc + (size_t)(u) * 128 * KDIM + (kt) * 32), \
        (__attribute__((address_space(3))) void*)(sBf + (bs) * 8192 + (u) * 4096 + sdst), 16, 0, 0);

    f32x4 acc[8][4] = {};

    // prologue: stage tiles 0 and 1 (8 loads), wait for tile 0 (4 left in flight)
    STAGE_A(0, 0, 0); STAGE_A(0, 0, 1); STAGE_B(0, 0, 0); STAGE_B(0, 0, 1);
    STAGE_A(1, 1, 0); STAGE_A(1, 1, 1); STAGE_B(1, 1, 0); STAGE_B(1, 1, 1);
    asm volatile("s_waitcnt vmcnt(4)" ::: "memory");
    __builtin_amdgcn_sched_barrier(0);
    __builtin_amdgcn_s_barrier();

    // invariant entering tile t: tiles <= t landed (all waves); only t+1's loads outstanding
    for (int t = 0; t < GT; ++t) {
        const int b  = t & 3;
        const int bs = (t + 2) & 3;
        const bool st = (t + 2 < GT);
        const unsigned short* sAb = sAf + b * 8192;
        const unsigned short* sBb = sBf + b * 8192;

        short8 bfr[4], afr[4], afr2[4];
#pragma unroll
        for (int j = 0; j < 4; ++j)
            bfr[j] = *reinterpret_cast<const short8*>(sBb + (wn + j * 16 + fr) * 32 + kqx * 8);
#pragma unroll
        for (int i = 0; i < 4; ++i)
            afr[i] = *reinterpret_cast<const short8*>(sAb + (wm + i * 16 + fr) * 32 + kqx * 8);
#pragma unroll
        for (int i = 0; i < 4; ++i)
            afr2[i] = *reinterpret_cast<const short8*>(sAb + (wm + 64 + i * 16 + fr) * 32 + kqx * 8);

        if (st) { STAGE_A(bs, t + 2, 0); STAGE_A(bs, t + 2, 1);
                  STAGE_B(bs, t + 2, 0); STAGE_B(bs, t + 2, 1); }

        __builtin_amdgcn_s_setprio(1);
#pragma unroll
        for (int i = 0; i < 4; ++i)
#pragma unroll
            for (int j = 0; j < 4; ++j)
                acc[i][j] = __builtin_amdgcn_mfma_f32_16x16x32_bf16(afr[i], bfr[j], acc[i][j], 0, 0, 0);
#pragma unroll
        for (int i = 0; i < 4; ++i)
#pragma unroll
            for (int j = 0; j < 4; ++j)
                acc[4 + i][j] = __builtin_amdgcn_mfma_f32_16x16x32_bf16(afr2[i], bfr[j], acc[4 + i][j], 0, 0, 0);
        __builtin_amdgcn_s_setprio(0);

        // single per-tile publish: tile t+1's loads must land before next tile's reads
        if (t < GT - 2) {
            asm volatile("s_waitcnt vmcnt(4)" ::: "memory");
        } else if (t == GT - 2) {
            asm volatile("s_waitcnt vmcnt(0)" ::: "memory");
        }
        __builtin_amdgcn_sched_barrier(0);
        __builtin_amdgcn_s_barrier();
    }
#undef STAGE_A
#undef STAGE_B

    // epilogue: C/D layout col=lane&15, row=(lane>>4)*4+reg
#pragma unroll
    for (int i = 0; i < 8; ++i) {
#pragma unroll
        for (int j = 0; j < 4; ++j) {
#pragma unroll
            for (int r = 0; r < 4; ++r) {
                int row = row0 + wm + i * 16 + kq * 4 + r;
                int col = col0 + wn + j * 16 + fr;
                C[(size_t)row * NCOLS + col] = f2bf(acc[i][j][r]);
            }
        }
    }
}

// ---------------- Scan phase 1: per-chunk aggregates (A = prod a, Y = local state)
// [c][ch] layout, coalesced float4 writes (reverts R4's scatter-store regression).
__global__ __launch_bounds__(256) void chunk_agg_kernel(const unsigned short* __restrict__ qkva,
                                                        float* __restrict__ Aagg,
                                                        float* __restrict__ Yagg) {
    const int c = blockIdx.x, b = blockIdx.y;
    const int d4 = threadIdx.x * 4;                  // channel group base (0..1020)
    const unsigned short* base = qkva + ((size_t)b * SEQ_N + c * CHUNK_L) * NCOLS;
    float s[4] = {0.f, 0.f, 0.f, 0.f};
    float A[4] = {1.f, 1.f, 1.f, 1.f};
#pragma unroll 4
    for (int n = 0; n < CHUNK_L; ++n) {
        const ushort4 kvu = *reinterpret_cast<const ushort4*>(base + (size_t)n * NCOLS + DIM + d4);
        const ushort4 au  = *reinterpret_cast<const ushort4*>(base + (size_t)n * NCOLS + 2 * DIM + d4);
        const float kv[4] = {bf2f(kvu.x), bf2f(kvu.y), bf2f(kvu.z), bf2f(kvu.w)};
        const float av[4] = {bf2f(au.x),  bf2f(au.y),  bf2f(au.z),  bf2f(au.w)};
#pragma unroll
        for (int j = 0; j < 4; ++j) {
            const float a = sigm(av[j]);
            s[j] = fmaf(a, s[j], kv[j]);
            A[j] *= a;
        }
    }
    const int idx = c * NCHANNEL + b * DIM + d4;
    float4 Ao, Yo;
    Ao.x = A[0]; Ao.y = A[1]; Ao.z = A[2]; Ao.w = A[3];
    Yo.x = s[0]; Yo.y = s[1]; Yo.z = s[2]; Yo.w = s[3];
    *reinterpret_cast<float4*>(&Aagg[idx]) = Ao;
    *reinterpret_cast<float4*>(&Yagg[idx]) = Yo;
}

// ---------------- Scan phase 2: LDS-transposed wave-parallel scan
// 64 blocks x 64 channels. Coalesced load of the [c][ch] aggregate slab into
// LDS (128KB), per-thread 64-chunk serial compose (thread t: channel t&63,
// segment t>>6), 4-segment compose in LDS, coalesced Sin[c][ch] emit.
__global__ __launch_bounds__(256) void agg_scan_kernel(const float* __restrict__ Aagg,
                                                       const float* __restrict__ Yagg,
                                                       float* __restrict__ Sin) {
    __shared__ float sA[NCHUNK][64];     // 64 KiB
    __shared__ float sY[NCHUNK][64];     // 64 KiB
    __shared__ float segA[4][64], segY[4][64];
    const int t = threadIdx.x;
    const int ch0 = blockIdx.x * 64;
    const int j = t & 63;                // channel within block
    const int g = t >> 6;                // segment (= wave id)
    // cooperative coalesced fill: wave g loads chunks c = i*4+g
#pragma unroll 8
    for (int i = 0; i < 64; ++i) {
        const int c = i * 4 + g;
        sA[c][j] = Aagg[(size_t)c * NCHANNEL + ch0 + j];
        sY[c][j] = Yagg[(size_t)c * NCHANNEL + ch0 + j];
    }
    __syncthreads();
    // per-thread serial compose of segment g (chunks g*64 .. g*64+63)
    float a = 1.f, y = 0.f;
#pragma unroll 8
    for (int i = 0; i < 64; ++i) {
        const int c = g * 64 + i;
        y = fmaf(sA[c][j], y, sY[c][j]);
        a *= sA[c][j];
    }
    segA[g][j] = a; segY[g][j] = y;
    __syncthreads();
    // entry state for segment g = compose of segments < g
    float s = 0.f;
#pragma unroll
    for (int gg = 0; gg < 3; ++gg)
        if (gg < g) s = fmaf(segA[gg][j], s, segY[gg][j]);
    // re-walk emitting entry states (coalesced: a wave shares c, ch consecutive)
#pragma unroll 8
    for (int i = 0; i < 64; ++i) {
        const int c = g * 64 + i;
        Sin[(size_t)c * NCHANNEL + ch0 + j] = s;
        s = fmaf(sA[c][j], s, sY[c][j]);
    }
}

// ---------------- Scan phase 3: rescan chunk with correct entry state, out = q*y
__global__ __launch_bounds__(256) void apply_kernel(const unsigned short* __restrict__ qkva,
                                                    const float* __restrict__ Sin,
                                                    float* __restrict__ out) {
    const int c = blockIdx.x, b = blockIdx.y;
    const int d4 = threadIdx.x * 4;
    const unsigned short* base = qkva + ((size_t)b * SEQ_N + c * CHUNK_L) * NCOLS;
    float* obase = out + ((size_t)b * SEQ_N + c * CHUNK_L) * DIM;
    const float4 s0 = *reinterpret_cast<const float4*>(&Sin[(size_t)c * NCHANNEL + b * DIM + d4]);
    float s[4] = {s0.x, s0.y, s0.z, s0.w};
#pragma unroll 4
    for (int n = 0; n < CHUNK_L; ++n) {
        const ushort4 qu  = *reinterpret_cast<const ushort4*>(base + (size_t)n * NCOLS + d4);
        const ushort4 kvu = *reinterpret_cast<const ushort4*>(base + (size_t)n * NCOLS + DIM + d4);
        const ushort4 au  = *reinterpret_cast<const ushort4*>(base + (size_t)n * NCOLS + 2 * DIM + d4);
        const float kv[4] = {bf2f(kvu.x), bf2f(kvu.y), bf2f(kvu.z), bf2f(kvu.w)};
        const float av[4] = {bf2f(au.x),  bf2f(au.y),  bf2f(au.z),  bf2f(au.w)};
        const float q[4]  = {bf2f(qu.x),  bf2f(qu.y),  bf2f(qu.z),  bf2f(qu.w)};
        float4 o;
#pragma unroll
        for (int j = 0; j < 4; ++j) {
            const float a = sigm(av[j]);
            s[j] = fmaf(a, s[j], kv[j]);
        }
        o.x = q[0] * s[0]; o.y = q[1] * s[1]; o.z = q[2] * s[2]; o.w = q[3] * s[3];
        *reinterpret_cast<float4*>(&obase[(size_t)n * DIM + d4]) = o;
    }
}

extern "C" void kernel_launch(void* const* d_in, const int* in_sizes, int n_in,
                              void* d_out, int out_size, void* d_ws, size_t ws_size,
                              hipStream_t stream) {
    const float* x     = (const float*)d_in[0];   // [4,4096,1024]
    const float* w     = (const float*)d_in[1];   // [3072,1024]
    const float* gamma = (const float*)d_in[2];   // [1024]
    float* out = (float*)d_out;                   // [4,4096,1024]

    char* ws = (char*)d_ws;
    // workspace layout (bytes):
    unsigned short* wb   = (unsigned short*)(ws);                         // 3072*1024*2   = 6,291,456
    unsigned short* h    = (unsigned short*)(ws + 6291456);               // 16384*1024*2  = 33,554,432
    unsigned short* qkva = (unsigned short*)(ws + 39845888);              // 16384*3072*2  = 100,663,296
    // scan temporaries alias the h region (h is dead after the GEMM):
    // NCHUNK*NCHANNEL*4 = 256*4096*4 = 4,194,304 each
    float* Aagg = (float*)(ws + 6291456);
    float* Yagg = (float*)(ws + 6291456 + 4194304);
    float* Sin  = (float*)(ws + 6291456 + 8388608);

    pre_kernel<<<WCONV_BLOCKS + M_ROWS, 256, 0, stream>>>(w, wb, x, gamma, h);
    gemm256_kernel<<<(M_ROWS / 256) * (NCOLS / 256), 512, 0, stream>>>(h, wb, qkva);
    chunk_agg_kernel<<<dim3(NCHUNK, BATCH), 256, 0, stream>>>(qkva, Aagg, Yagg);
    agg_scan_kernel<<<NCHANNEL / 64, 256, 0, stream>>>(Aagg, Yagg, Sin);
    apply_kernel<<<dim3(NCHUNK, BATCH), 256, 0, stream>>>(qkva, Sin, out);
}